// Round 1
// 497.795 us; speedup vs baseline: 1.1259x; 1.1259x over previous
//
#include <hip/hip_runtime.h>
#include <stdint.h>

#define IN_F  4096
#define OUT_F 4096

typedef unsigned short u16;
typedef __attribute__((ext_vector_type(8))) short bf16x8;
typedef __attribute__((ext_vector_type(4))) float f32x4;

__device__ __forceinline__ u16 f2bf(float f) {
    union { float f; unsigned u; } c; c.f = f;
    unsigned u = c.u;
    return (u16)((u + 0x7FFFu + ((u >> 16) & 1u)) >> 16);
}
__device__ __forceinline__ float bf2f(u16 h) {
    union { unsigned u; float f; } c; c.u = ((unsigned)h) << 16;
    return c.f;
}

// async global->LDS, 16B per lane. LDS dest is wave-uniform base + lane*16.
__device__ __forceinline__ void load_lds16(const void* g, void* l) {
    unsigned loff = (unsigned)(uintptr_t)l;
    loff = (unsigned)__builtin_amdgcn_readfirstlane((int)loff);
    __builtin_amdgcn_global_load_lds(
        (const __attribute__((address_space(1))) void*)(uintptr_t)g,
        (__attribute__((address_space(3))) void*)(uintptr_t)loff,
        16, 0, 0);
}

// ---------------------------------------------------------------------------
// Kernel 1: fused dequant + CSR outliers -> W bf16 [OUT][IN]  (unchanged)
// ---------------------------------------------------------------------------
#define DQ_O 64
#define DQ_I 256   // 32 packed words

__global__ __launch_bounds__(256) void dequant_k(const int* __restrict__ qw,
                                                 const float* __restrict__ lut,
                                                 const int* __restrict__ rows,
                                                 const int* __restrict__ cols,
                                                 const float* __restrict__ vals,
                                                 u16* __restrict__ W) {
    __shared__ __align__(16) u16 sW[DQ_O * DQ_I];   // 32 KB
    __shared__ u16 slut[DQ_O * 18];                 // padded stride 18 (9 dw, odd)

    const int tid = threadIdx.x;
    const int o0 = blockIdx.y * DQ_O;
    const int i0 = blockIdx.x * DQ_I;
    const int p0 = i0 >> 3;

    {
        const int idx = tid * 4;
        const float4 v = *(const float4*)(lut + (size_t)o0 * 16 + idx);
        u16* d = slut + (idx >> 4) * 18 + (idx & 15);
        d[0] = f2bf(v.x); d[1] = f2bf(v.y); d[2] = f2bf(v.z); d[3] = f2bf(v.w);
    }
    __syncthreads();

    const int o_l = tid & 63;
    const int swz = o_l & 31;
#pragma unroll
    for (int it = 0; it < 8; ++it) {
        const int p = (tid >> 6) + it * 4;                       // 0..31
        const unsigned w = (unsigned)qw[(size_t)(p0 + p) * OUT_F + (o0 + o_l)];
        union { u16 h[8]; uint4 v; } u;
#pragma unroll
        for (int j = 0; j < 8; ++j)
            u.h[j] = slut[o_l * 18 + ((w >> (4 * j)) & 15u)];
        *(uint4*)(sW + o_l * DQ_I + ((p ^ swz) << 3)) = u.v;
    }
    __syncthreads();

    if (tid < DQ_O) {
        const int s = rows[o0 + tid], e = rows[o0 + tid + 1];
        for (int k = s; k < e; ++k) {
            const unsigned j = (unsigned)(cols[k] - i0);
            if (j < DQ_I) {
                u16* p16 = sW + tid * DQ_I + (((j >> 3) ^ swz) << 3) + (j & 7);
                *p16 = f2bf(bf2f(*p16) + vals[k]);
            }
        }
    }
    __syncthreads();

    const int ch = tid & 31;
#pragma unroll
    for (int it = 0; it < 8; ++it) {
        const int r = (tid >> 5) + it * 8;                       // 0..63
        *(uint4*)(W + (size_t)(o0 + r) * IN_F + i0 + ch * 8) =
            *(const uint4*)(sW + r * DQ_I + ((ch ^ (r & 31)) << 3));
    }
}

// ---------------------------------------------------------------------------
// Kernel 2: x fp32 -> bf16 (RNE).  (unchanged)
// ---------------------------------------------------------------------------
__global__ __launch_bounds__(256) void cvtx_k(const float4* __restrict__ x,
                                              u16* __restrict__ xb) {
    const size_t i = (size_t)blockIdx.x * 256 + threadIdx.x;
    const float4 a = x[2 * i];
    const float4 b = x[2 * i + 1];
    union { u16 h[8]; uint4 v; } u;
    u.h[0] = f2bf(a.x); u.h[1] = f2bf(a.y); u.h[2] = f2bf(a.z); u.h[3] = f2bf(a.w);
    u.h[4] = f2bf(b.x); u.h[5] = f2bf(b.y); u.h[6] = f2bf(b.z); u.h[7] = f2bf(b.w);
    *(uint4*)(xb + i * 8) = u.v;
}

// ---------------------------------------------------------------------------
// Kernel 3: GEMM  y[M][N] = A[M][K] * B[N][K]^T + bias   (A,B bf16; y fp32)
// 256x256 tile, 8 waves (2M x 4N, each 128x64), 8-phase schedule:
//   - K split into 32-wide chunks; 4-slot LDS ring per operand
//     (slot = [256 rows][32 k] bf16 = 16KB; total LDS = 128KB).
//   - slot s consumed at phases 2s+1,2s+2 (16 MFMA each), restaged at
//     phases 2s+3,2s+4 (2 global_load_lds per phase) -> every WAR is
//     barrier-separated, prefetch lead ~5 phases.
//   - counted s_waitcnt vmcnt(4) at phases 4 and 8 ONLY (4 loads stay in
//     flight across each wait; never drain to 0 in the main loop).
//   - swizzle both-sides: LDS linear for global_load_lds, global SOURCE
//     pre-swizzled byte^=((row>>1)&3)<<4, same XOR on ds_read side
//     -> 2-way start-bank (free) instead of 8-way.
// ---------------------------------------------------------------------------
#define GK 4096

#define MF(A_, B_, C_) __builtin_amdgcn_mfma_f32_16x16x32_bf16(A_, B_, C_, 0, 0, 0)

#define ROW(M_, AV)                                   \
    acc[M_][0] = MF(AV, b0, acc[M_][0]);              \
    acc[M_][1] = MF(AV, b1, acc[M_][1]);              \
    acc[M_][2] = MF(AV, b2, acc[M_][2]);              \
    acc[M_][3] = MF(AV, b3, acc[M_][3]);

#define STAGE_A(SLOT, KC) do {                                              \
    load_lds16(srcA0 + (KC) * 64, ldsA + (SLOT) * 16384 + ldst);            \
    load_lds16(srcA1 + (KC) * 64, ldsA + (SLOT) * 16384 + 8192 + ldst);     \
  } while (0)
#define STAGE_B(SLOT, KC) do {                                              \
    load_lds16(srcB0 + (KC) * 64, ldsB + (SLOT) * 16384 + ldst);            \
    load_lds16(srcB1 + (KC) * 64, ldsB + (SLOT) * 16384 + 8192 + ldst);     \
  } while (0)

#define WAIT4 asm volatile("s_waitcnt vmcnt(4)" ::: "memory")
#define VNOP  ((void)0)

// phase reading rows 0-3 of the wave tile (loads B frags too)
#define PH_LO(SLOT, STAGE, WAIT)                                            \
  { const char* pa = ldsA + (SLOT) * 16384;                                 \
    const char* pb = ldsB + (SLOT) * 16384;                                 \
    a0 = *(const bf16x8*)(pa + offA0);                                      \
    a1 = *(const bf16x8*)(pa + offA1);                                      \
    a2 = *(const bf16x8*)(pa + offA2);                                      \
    a3 = *(const bf16x8*)(pa + offA3);                                      \
    b0 = *(const bf16x8*)(pb + offB0);                                      \
    b1 = *(const bf16x8*)(pb + offB1);                                      \
    b2 = *(const bf16x8*)(pb + offB2);                                      \
    b3 = *(const bf16x8*)(pb + offB3);                                      \
    STAGE;                                                                  \
    __builtin_amdgcn_s_barrier();                                           \
    asm volatile("s_waitcnt lgkmcnt(0)" ::: "memory");                      \
    __builtin_amdgcn_s_setprio(1);                                          \
    ROW(0, a0) ROW(1, a1) ROW(2, a2) ROW(3, a3)                             \
    __builtin_amdgcn_s_setprio(0);                                          \
    WAIT;                                                                   \
    __builtin_amdgcn_s_barrier(); }

// phase reading rows 4-7 of the wave tile (reuses B frags)
#define PH_HI(SLOT, STAGE, WAIT)                                            \
  { const char* pa = ldsA + (SLOT) * 16384;                                 \
    a0 = *(const bf16x8*)(pa + offA4);                                      \
    a1 = *(const bf16x8*)(pa + offA5);                                      \
    a2 = *(const bf16x8*)(pa + offA6);                                      \
    a3 = *(const bf16x8*)(pa + offA7);                                      \
    STAGE;                                                                  \
    __builtin_amdgcn_s_barrier();                                           \
    asm volatile("s_waitcnt lgkmcnt(0)" ::: "memory");                      \
    __builtin_amdgcn_s_setprio(1);                                          \
    ROW(4, a0) ROW(5, a1) ROW(6, a2) ROW(7, a3)                             \
    __builtin_amdgcn_s_setprio(0);                                          \
    WAIT;                                                                   \
    __builtin_amdgcn_s_barrier(); }

__global__ __launch_bounds__(512, 2) void gemm8_k(const u16* __restrict__ A,
                                                  const u16* __restrict__ B,
                                                  const float* __restrict__ bias,
                                                  float* __restrict__ C,
                                                  int M, int N) {
    __shared__ __align__(16) u16 sAq[4 * 256 * 32];   // 64 KB
    __shared__ __align__(16) u16 sBq[4 * 256 * 32];   // 64 KB

    const int tid  = threadIdx.x;
    const int wave = tid >> 6;
    const int lane = tid & 63;

    // XCD-aware bijective block swizzle (nwg % 8 == 0 here: 512)
    const int ntx = N >> 8;
    const int nwg = (M >> 8) * ntx;
    const int cpx = nwg >> 3;
    const int bid = blockIdx.x;
    const int wg  = (bid & 7) * cpx + (bid >> 3);
    const int bm = (wg / ntx) << 8;
    const int bn = (wg % ntx) << 8;

    // ---- staging: per-thread global source (pre-swizzled), linear LDS dest
    const int r4  = tid >> 2;                                  // 0..127
    const int cbs = ((tid & 3) << 4) ^ (((r4 >> 1) & 3) << 4); // swizzled 16B slot
    const char* srcA0 = (const char*)A + ((size_t)(bm + r4) * GK) * 2 + cbs;
    const char* srcA1 = (const char*)A + ((size_t)(bm + 128 + r4) * GK) * 2 + cbs;
    const char* srcB0 = (const char*)B + ((size_t)(bn + r4) * GK) * 2 + cbs;
    const char* srcB1 = (const char*)B + ((size_t)(bn + 128 + r4) * GK) * 2 + cbs;

    char* ldsA = (char*)sAq;
    char* ldsB = (char*)sBq;
    const int ldst = wave << 10;   // wave-uniform 1KB chunk within 8KB half

    // ---- fragment read offsets (swizzle baked in, thread-invariant)
    const int frow = lane & 15;
    const int fk2  = (lane >> 4) << 4;          // 16B k-slot
    const int wmr  = (wave >> 2) << 7;          // 0 / 128
    const int wnr  = (wave & 3) << 6;           // 0 / 64 / 128 / 192
#define AOFF(m_) ((((wmr + (m_) * 16 + frow)) << 6) + \
                  (fk2 ^ ((((wmr + (m_) * 16 + frow) >> 1) & 3) << 4)))
#define BOFF(n_) ((((wnr + (n_) * 16 + frow)) << 6) + \
                  (fk2 ^ ((((wnr + (n_) * 16 + frow) >> 1) & 3) << 4)))
    const int offA0 = AOFF(0), offA1 = AOFF(1), offA2 = AOFF(2), offA3 = AOFF(3);
    const int offA4 = AOFF(4), offA5 = AOFF(5), offA6 = AOFF(6), offA7 = AOFF(7);
    const int offB0 = BOFF(0), offB1 = BOFF(1), offB2 = BOFF(2), offB3 = BOFF(3);
#undef AOFF
#undef BOFF

    f32x4 acc[8][4] = {};
    bf16x8 a0, a1, a2, a3, b0, b1, b2, b3;

    // ---- prologue: stage k-chunks 0,1,2 into slots 0,1,2 (12 loads),
    //      drain to 4 outstanding (slot2 stays in flight, covered by ph4 wait)
    STAGE_A(0, 0); STAGE_B(0, 0);
    STAGE_A(1, 1); STAGE_B(1, 1);
    STAGE_A(2, 2); STAGE_B(2, 2);
    WAIT4;
    __builtin_amdgcn_s_barrier();

    // ---- main loop: 32 iters x 4 k-chunks (k advances 128/iter)
    for (int it = 0; it < 32; ++it) {
        const int c   = it * 4;
        const int kc3 = c + 3;
        const int kc4 = (c + 4) & 127;   // wrap on last iter: harmless refetch
        const int kc5 = (c + 5) & 127;
        const int kc6 = (c + 6) & 127;

        PH_LO(0, STAGE_A(3, kc3), VNOP)   // ph1: consume slot0, stage slot3.A
        PH_HI(0, STAGE_B(3, kc3), VNOP)   // ph2:                stage slot3.B
        PH_LO(1, STAGE_A(0, kc4), VNOP)   // ph3: consume slot1, stage slot0.A
        PH_HI(1, STAGE_B(0, kc4), WAIT4)  // ph4: vmcnt(4) -> slot2,slot3 ready
        PH_LO(2, STAGE_A(1, kc5), VNOP)   // ph5: consume slot2, stage slot1.A
        PH_HI(2, STAGE_B(1, kc5), VNOP)   // ph6:                stage slot1.B
        PH_LO(3, STAGE_A(2, kc6), VNOP)   // ph7: consume slot3, stage slot2.A
        PH_HI(3, STAGE_B(2, kc6), WAIT4)  // ph8: vmcnt(4) -> slot0,slot1 ready
    }

    // ---- epilogue: C = acc + bias
    const int cm = bm + wmr;
    const int cn = bn + wnr;
#pragma unroll
    for (int n = 0; n < 4; ++n) {
        const int col = cn + n * 16 + frow;
        const float bv = bias[col];
#pragma unroll
        for (int m = 0; m < 8; ++m) {
            const int r0 = cm + m * 16 + (lane >> 4) * 4;
#pragma unroll
            for (int r = 0; r < 4; ++r)
                C[(size_t)(r0 + r) * N + col] = acc[m][n][r] + bv;
        }
    }
}

// ---------------------------------------------------------------------------
extern "C" void kernel_launch(void* const* d_in, const int* in_sizes, int n_in,
                              void* d_out, int out_size, void* d_ws, size_t ws_size,
                              hipStream_t stream) {
    (void)n_in; (void)out_size; (void)ws_size;
    const float* x     = (const float*)d_in[0];
    const float* lut   = (const float*)d_in[1];
    const float* bias  = (const float*)d_in[2];
    const float* ovals = (const float*)d_in[3];
    const int*   qw    = (const int*)d_in[4];
    const int*   orows = (const int*)d_in[5];
    const int*   ocols = (const int*)d_in[6];
    float* y = (float*)d_out;

    const int M = in_sizes[0] / IN_F;   // 8192

    u16* W  = (u16*)d_ws;                                        // 32 MB
    u16* xb = (u16*)((char*)d_ws + (size_t)OUT_F * IN_F * 2);    // 64 MB

    dim3 dq_grid(IN_F / DQ_I, OUT_F / DQ_O);
    dequant_k<<<dq_grid, 256, 0, stream>>>(qw, lut, orows, ocols, ovals, W);
    cvtx_k<<<(size_t)M * IN_F / 8 / 256, 256, 0, stream>>>((const float4*)x, xb);

    const int nwg = (M / 256) * (OUT_F / 256);                   // 512
    gemm8_k<<<dim3(nwg), dim3(512), 0, stream>>>(xb, W, bias, y, M, OUT_F);
}

// Round 2
// 471.630 us; speedup vs baseline: 1.1884x; 1.0555x over previous
//
#include <hip/hip_runtime.h>
#include <stdint.h>

#define IN_F  4096
#define OUT_F 4096

typedef unsigned short u16;
typedef __attribute__((ext_vector_type(8))) short bf16x8;
typedef __attribute__((ext_vector_type(4))) float f32x4;

__device__ __forceinline__ u16 f2bf(float f) {
    union { float f; unsigned u; } c; c.f = f;
    unsigned u = c.u;
    return (u16)((u + 0x7FFFu + ((u >> 16) & 1u)) >> 16);
}
__device__ __forceinline__ float bf2f(u16 h) {
    union { unsigned u; float f; } c; c.u = ((unsigned)h) << 16;
    return c.f;
}

// async global->LDS, 16B per lane. LDS dest is wave-uniform base + lane*16.
__device__ __forceinline__ void load_lds16(const void* g, void* l) {
    unsigned loff = (unsigned)(uintptr_t)l;
    loff = (unsigned)__builtin_amdgcn_readfirstlane((int)loff);
    __builtin_amdgcn_global_load_lds(
        (const __attribute__((address_space(1))) void*)(uintptr_t)g,
        (__attribute__((address_space(3))) void*)(uintptr_t)loff,
        16, 0, 0);
}

// ---------------------------------------------------------------------------
// Kernel 1: MERGED prep kernel.
//   blocks [0, 1024):      fused dequant + CSR outliers -> W bf16 [OUT][IN]
//   blocks [1024, 17408):  x fp32 -> bf16 (RNE), 8 floats/thread
// Merging overlaps the CSR serial-walk tail with the streaming convert and
// removes one launch.
// ---------------------------------------------------------------------------
#define DQ_O 64
#define DQ_I 256   // 32 packed words
#define DQ_BLOCKS ((IN_F / DQ_I) * (OUT_F / DQ_O))   // 1024

__global__ __launch_bounds__(256) void prep_k(const int* __restrict__ qw,
                                              const float* __restrict__ lut,
                                              const int* __restrict__ rows,
                                              const int* __restrict__ cols,
                                              const float* __restrict__ vals,
                                              u16* __restrict__ W,
                                              const float4* __restrict__ x,
                                              u16* __restrict__ xb) {
    __shared__ __align__(16) u16 sW[DQ_O * DQ_I];   // 32 KB
    __shared__ u16 slut[DQ_O * 18];                 // padded stride 18

    const int tid = threadIdx.x;

    if (blockIdx.x >= DQ_BLOCKS) {
        // ---- cvtx part: pure streaming convert
        const size_t i = (size_t)(blockIdx.x - DQ_BLOCKS) * 256 + tid;
        const float4 a = x[2 * i];
        const float4 b = x[2 * i + 1];
        union { u16 h[8]; uint4 v; } u;
        u.h[0] = f2bf(a.x); u.h[1] = f2bf(a.y); u.h[2] = f2bf(a.z); u.h[3] = f2bf(a.w);
        u.h[4] = f2bf(b.x); u.h[5] = f2bf(b.y); u.h[6] = f2bf(b.z); u.h[7] = f2bf(b.w);
        *(uint4*)(xb + i * 8) = u.v;
        return;
    }

    // ---- dequant part
    const int o0 = (blockIdx.x >> 4) * DQ_O;          // 64 o-blocks
    const int i0 = (blockIdx.x & 15) * DQ_I;          // 16 i-blocks
    const int p0 = i0 >> 3;

    {
        const int idx = tid * 4;
        const float4 v = *(const float4*)(lut + (size_t)o0 * 16 + idx);
        u16* d = slut + (idx >> 4) * 18 + (idx & 15);
        d[0] = f2bf(v.x); d[1] = f2bf(v.y); d[2] = f2bf(v.z); d[3] = f2bf(v.w);
    }
    __syncthreads();

    const int o_l = tid & 63;
    const int swz = o_l & 31;
#pragma unroll
    for (int it = 0; it < 8; ++it) {
        const int p = (tid >> 6) + it * 4;                       // 0..31
        const unsigned w = (unsigned)qw[(size_t)(p0 + p) * OUT_F + (o0 + o_l)];
        union { u16 h[8]; uint4 v; } u;
#pragma unroll
        for (int j = 0; j < 8; ++j)
            u.h[j] = slut[o_l * 18 + ((w >> (4 * j)) & 15u)];
        *(uint4*)(sW + o_l * DQ_I + ((p ^ swz) << 3)) = u.v;
    }
    __syncthreads();

    // CSR outliers: one thread per o-row. 4x unrolled load batching (ILP),
    // serial APPLICATION preserved (duplicate cols must add in order).
    if (tid < DQ_O) {
        const int s = rows[o0 + tid], e = rows[o0 + tid + 1];
        int k = s;
#define APPLY(CJ, VV) do {                                                  \
        const unsigned j_ = (unsigned)((CJ) - i0);                          \
        if (j_ < DQ_I) {                                                    \
            u16* p16 = sW + tid * DQ_I + (((j_ >> 3) ^ swz) << 3) + (j_ & 7); \
            *p16 = f2bf(bf2f(*p16) + (VV));                                 \
        } } while (0)
        for (; k + 4 <= e; k += 4) {
            const int c0 = cols[k], c1 = cols[k + 1], c2 = cols[k + 2], c3 = cols[k + 3];
            const float v0 = vals[k], v1 = vals[k + 1], v2 = vals[k + 2], v3 = vals[k + 3];
            APPLY(c0, v0); APPLY(c1, v1); APPLY(c2, v2); APPLY(c3, v3);
        }
        for (; k < e; ++k) APPLY(cols[k], vals[k]);
#undef APPLY
    }
    __syncthreads();

    const int ch = tid & 31;
#pragma unroll
    for (int it = 0; it < 8; ++it) {
        const int r = (tid >> 5) + it * 8;                       // 0..63
        *(uint4*)(W + (size_t)(o0 + r) * IN_F + i0 + ch * 8) =
            *(const uint4*)(sW + r * DQ_I + ((ch ^ (r & 31)) << 3));
    }
}

// ---------------------------------------------------------------------------
// Kernel 2: GEMM  y[M][N] = A[M][K] * B[N][K]^T + bias   (A,B bf16; y fp32)
// 256x256 tile, 8 waves (2M x 4N, each 128x64), 8-phase schedule v2:
//   - 4-slot LDS ring per operand (slot = [256][32] bf16 = 16KB; 128KB total).
//   - FRAGMENT READS PIPELINED ONE PHASE AHEAD (register double-buffer
//     aA/aB, bA/bB): phase p issues ds_reads for phase p+1; MFMA_p consumes
//     regs loaded at p-1 -> LDS drain overlaps MFMA. Compiler inserts the
//     counted lgkmcnt automatically (reads are register-visible).
//   - vmcnt(4) at end of EVERY EVEN phase: slot staged at phases q-1,q is
//     still in flight; everything older drained -> each slot is published
//     (landed + barrier) >= 1 phase before its first fragment read.
//   - ONE barrier per phase (publication + WAR; staged-slot != consumed-slot
//     in every phase, so no same-slot race).
//   - swizzle both-sides: linear LDS dest, pre-swizzled global source,
//     same XOR on read side. Swizzle term ((frow>>1)&3)<<4 is independent
//     of the m/n fragment index -> all frag addrs = 2 VGPR bases + imms.
// ---------------------------------------------------------------------------
#define GK 4096

#define MF(A_, B_, C_) __builtin_amdgcn_mfma_f32_16x16x32_bf16(A_, B_, C_, 0, 0, 0)

#define STAGE_A(SLOT, KC) do {                                              \
    load_lds16(srcA0 + (KC) * 64, ldsA + (SLOT) * 16384 + ldst);            \
    load_lds16(srcA1 + (KC) * 64, ldsA + (SLOT) * 16384 + 8192 + ldst);     \
  } while (0)
#define STAGE_B(SLOT, KC) do {                                              \
    load_lds16(srcB0 + (KC) * 64, ldsB + (SLOT) * 16384 + ldst);            \
    load_lds16(srcB1 + (KC) * 64, ldsB + (SLOT) * 16384 + 8192 + ldst);     \
  } while (0)

#define WAIT4 asm volatile("s_waitcnt vmcnt(4)" ::: "memory")
#define VNOP  ((void)0)

#define LDA(S, M) (*(const bf16x8*)(ldsA + (S) * 16384 + (M) * 1024 + aoff))
#define LDB(S, N) (*(const bf16x8*)(ldsB + (S) * 16384 + (N) * 1024 + boff))

#define RD_ALO(S) aA0 = LDA(S, 0); aA1 = LDA(S, 1); aA2 = LDA(S, 2); aA3 = LDA(S, 3)
#define RD_AHI(S) aB0 = LDA(S, 4); aB1 = LDA(S, 5); aB2 = LDA(S, 6); aB3 = LDA(S, 7)
#define RD_BA(S)  bA0 = LDB(S, 0); bA1 = LDB(S, 1); bA2 = LDB(S, 2); bA3 = LDB(S, 3)
#define RD_BB(S)  bB0 = LDB(S, 0); bB1 = LDB(S, 1); bB2 = LDB(S, 2); bB3 = LDB(S, 3)

#define MFMA16(A0, A1, A2, A3, B0, B1, B2, B3, R)                           \
    acc[(R)+0][0] = MF(A0, B0, acc[(R)+0][0]);                              \
    acc[(R)+0][1] = MF(A0, B1, acc[(R)+0][1]);                              \
    acc[(R)+0][2] = MF(A0, B2, acc[(R)+0][2]);                              \
    acc[(R)+0][3] = MF(A0, B3, acc[(R)+0][3]);                              \
    acc[(R)+1][0] = MF(A1, B0, acc[(R)+1][0]);                              \
    acc[(R)+1][1] = MF(A1, B1, acc[(R)+1][1]);                              \
    acc[(R)+1][2] = MF(A1, B2, acc[(R)+1][2]);                              \
    acc[(R)+1][3] = MF(A1, B3, acc[(R)+1][3]);                              \
    acc[(R)+2][0] = MF(A2, B0, acc[(R)+2][0]);                              \
    acc[(R)+2][1] = MF(A2, B1, acc[(R)+2][1]);                              \
    acc[(R)+2][2] = MF(A2, B2, acc[(R)+2][2]);                              \
    acc[(R)+2][3] = MF(A2, B3, acc[(R)+2][3]);                              \
    acc[(R)+3][0] = MF(A3, B0, acc[(R)+3][0]);                              \
    acc[(R)+3][1] = MF(A3, B1, acc[(R)+3][1]);                              \
    acc[(R)+3][2] = MF(A3, B2, acc[(R)+3][2]);                              \
    acc[(R)+3][3] = MF(A3, B3, acc[(R)+3][3]);

#define PHASE(RDNEXT, STG, A0, A1, A2, A3, B0, B1, B2, B3, R, VM)           \
  { RDNEXT;                                                                 \
    STG;                                                                    \
    __builtin_amdgcn_s_setprio(1);                                          \
    MFMA16(A0, A1, A2, A3, B0, B1, B2, B3, R)                               \
    __builtin_amdgcn_s_setprio(0);                                          \
    VM;                                                                     \
    __builtin_amdgcn_s_barrier(); }

__global__ __launch_bounds__(512, 2) void gemm8_k(const u16* __restrict__ A,
                                                  const u16* __restrict__ B,
                                                  const float* __restrict__ bias,
                                                  float* __restrict__ C,
                                                  int M, int N) {
    __shared__ __align__(16) u16 sAq[4 * 256 * 32];   // 64 KB
    __shared__ __align__(16) u16 sBq[4 * 256 * 32];   // 64 KB

    const int tid  = threadIdx.x;
    const int wave = tid >> 6;
    const int lane = tid & 63;

    // XCD-aware bijective block swizzle (nwg % 8 == 0 here: 512)
    const int ntx = N >> 8;
    const int nwg = (M >> 8) * ntx;
    const int cpx = nwg >> 3;
    const int bid = blockIdx.x;
    const int wg  = (bid & 7) * cpx + (bid >> 3);
    const int bm = (wg / ntx) << 8;
    const int bn = (wg % ntx) << 8;

    // ---- staging: per-thread global source (pre-swizzled), linear LDS dest
    const int r4  = tid >> 2;                                  // 0..127
    const int cbs = ((tid & 3) << 4) ^ (((r4 >> 1) & 3) << 4); // swizzled 16B slot
    const char* srcA0 = (const char*)A + ((size_t)(bm + r4) * GK) * 2 + cbs;
    const char* srcA1 = (const char*)A + ((size_t)(bm + 128 + r4) * GK) * 2 + cbs;
    const char* srcB0 = (const char*)B + ((size_t)(bn + r4) * GK) * 2 + cbs;
    const char* srcB1 = (const char*)B + ((size_t)(bn + 128 + r4) * GK) * 2 + cbs;

    char* ldsA = (char*)sAq;
    char* ldsB = (char*)sBq;
    const int ldst = wave << 10;   // wave-uniform 1KB chunk within 8KB half

    // ---- fragment read bases (swizzle independent of m/n -> imm offsets)
    const int frow = lane & 15;
    const int fk2  = (lane >> 4) << 4;          // 16B k-slot
    const int fswz = ((frow >> 1) & 3) << 4;
    const int wmr  = (wave >> 2) << 7;          // 0 / 128
    const int wnr  = (wave & 3) << 6;           // 0 / 64 / 128 / 192
    const int aoff = ((wmr + frow) << 6) + (fk2 ^ fswz);
    const int boff = ((wnr + frow) << 6) + (fk2 ^ fswz);

    f32x4 acc[8][4] = {};
    bf16x8 aA0, aA1, aA2, aA3, aB0, aB1, aB2, aB3;
    bf16x8 bA0, bA1, bA2, bA3, bB0, bB1, bB2, bB3;

    // ---- prologue: stage chunks 0,1,2 into slots 0,1,2 (12 loads);
    //      vmcnt(4) -> slots 0,1 landed (slot2 published at first ph2).
    STAGE_A(0, 0); STAGE_B(0, 0);
    STAGE_A(1, 1); STAGE_B(1, 1);
    STAGE_A(2, 2); STAGE_B(2, 2);
    WAIT4;
    __builtin_amdgcn_s_barrier();
    RD_ALO(0); RD_BA(0);

    // ---- main loop: 32 iters x 4 k-chunks (k advances 128/iter)
    for (int it = 0; it < 32; ++it) {
        const int c   = it * 4;
        const int kc3 = c + 3;
        const int kc4 = (c + 4) & 127;   // wrap on last iter: harmless refetch
        const int kc5 = (c + 5) & 127;
        const int kc6 = (c + 6) & 127;

        PHASE(RD_AHI(0),            STAGE_A(3, kc3), aA0, aA1, aA2, aA3, bA0, bA1, bA2, bA3, 0, VNOP)
        PHASE(RD_ALO(1); RD_BB(1),  STAGE_B(3, kc3), aB0, aB1, aB2, aB3, bA0, bA1, bA2, bA3, 4, WAIT4)
        PHASE(RD_AHI(1),            STAGE_A(0, kc4), aA0, aA1, aA2, aA3, bB0, bB1, bB2, bB3, 0, VNOP)
        PHASE(RD_ALO(2); RD_BA(2),  STAGE_B(0, kc4), aB0, aB1, aB2, aB3, bB0, bB1, bB2, bB3, 4, WAIT4)
        PHASE(RD_AHI(2),            STAGE_A(1, kc5), aA0, aA1, aA2, aA3, bA0, bA1, bA2, bA3, 0, VNOP)
        PHASE(RD_ALO(3); RD_BB(3),  STAGE_B(1, kc5), aB0, aB1, aB2, aB3, bA0, bA1, bA2, bA3, 4, WAIT4)
        PHASE(RD_AHI(3),            STAGE_A(2, kc6), aA0, aA1, aA2, aA3, bB0, bB1, bB2, bB3, 0, VNOP)
        PHASE(RD_ALO(0); RD_BA(0),  STAGE_B(2, kc6), aB0, aB1, aB2, aB3, bB0, bB1, bB2, bB3, 4, WAIT4)
    }

    // ---- epilogue: C = acc + bias
    const int cm = bm + wmr;
    const int cn = bn + wnr;
#pragma unroll
    for (int n = 0; n < 4; ++n) {
        const int col = cn + n * 16 + frow;
        const float bv = bias[col];
#pragma unroll
        for (int m = 0; m < 8; ++m) {
            const int r0 = cm + m * 16 + (lane >> 4) * 4;
#pragma unroll
            for (int r = 0; r < 4; ++r)
                C[(size_t)(r0 + r) * N + col] = acc[m][n][r] + bv;
        }
    }
}

// ---------------------------------------------------------------------------
extern "C" void kernel_launch(void* const* d_in, const int* in_sizes, int n_in,
                              void* d_out, int out_size, void* d_ws, size_t ws_size,
                              hipStream_t stream) {
    (void)n_in; (void)out_size; (void)ws_size;
    const float* x     = (const float*)d_in[0];
    const float* lut   = (const float*)d_in[1];
    const float* bias  = (const float*)d_in[2];
    const float* ovals = (const float*)d_in[3];
    const int*   qw    = (const int*)d_in[4];
    const int*   orows = (const int*)d_in[5];
    const int*   ocols = (const int*)d_in[6];
    float* y = (float*)d_out;

    const int M = in_sizes[0] / IN_F;   // 8192

    u16* W  = (u16*)d_ws;                                        // 32 MB
    u16* xb = (u16*)((char*)d_ws + (size_t)OUT_F * IN_F * 2);    // 64 MB

    const int cvt_blocks = (int)((size_t)M * IN_F / 8 / 256);    // 16384
    prep_k<<<DQ_BLOCKS + cvt_blocks, 256, 0, stream>>>(
        qw, lut, orows, ocols, ovals, W, (const float4*)x, xb);

    const int nwg = (M / 256) * (OUT_F / 256);                   // 512
    gemm8_k<<<dim3(nwg), dim3(512), 0, stream>>>(xb, W, bias, y, M, OUT_F);
}